// Round 5
// baseline (139.871 us; speedup 1.0000x reference)
//
#include <hip/hip_runtime.h>
#include <hip/hip_bf16.h>

typedef __attribute__((ext_vector_type(8))) short short8;
typedef __attribute__((ext_vector_type(4))) float floatx4;
typedef __attribute__((ext_vector_type(4))) unsigned int uintx4;

// accurate pack (conv kernel only)
__device__ __forceinline__ unsigned pack2_bf16_rn(float a, float b) {
  __hip_bfloat162 h = __float22bfloat162_rn(make_float2(a, b));
  unsigned r;
  __builtin_memcpy(&r, &h, 4);
  return r;
}

// fast pack: +0x8000 (RN ties-away, inputs finite) + byte perm. 3 VALU ops.
__device__ __forceinline__ unsigned pack2_bf16_fast(float a, float b) {
  unsigned ua, ub;
  __builtin_memcpy(&ua, &a, 4);
  __builtin_memcpy(&ub, &b, 4);
  return __builtin_amdgcn_perm(ub + 0x8000u, ua + 0x8000u, 0x07060302u);
}

// tanh + Legendre P1..P8 -> 8-bf16 MFMA A-fragment (~26 math + 12 pack VALU)
__device__ __forceinline__ short8 legendre_frag(float xv) {
  float e  = __builtin_amdgcn_exp2f(xv * 2.885390081777927f); // 2*log2(e)
  float t  = 1.0f - 2.0f * __builtin_amdgcn_rcpf(e + 1.0f);
  float p1 = t;
  float u2 = t * p1,  w2 = u2 - 1.0f;  float p2 = fmaf(0.5f, w2, u2);
  float u3 = t * p2,  w3 = u3 - p1;    float p3 = fmaf(2.0f/3.0f, w3, u3);
  float u4 = t * p3,  w4 = u4 - p2;    float p4 = fmaf(0.75f, w4, u4);
  float u5 = t * p4,  w5 = u5 - p3;    float p5 = fmaf(0.8f, w5, u5);
  float u6 = t * p5,  w6 = u6 - p4;    float p6 = fmaf(5.0f/6.0f, w6, u6);
  float u7 = t * p6,  w7 = u7 - p5;    float p7 = fmaf(6.0f/7.0f, w7, u7);
  float u8 = t * p7,  w8 = u8 - p6;    float p8 = fmaf(7.0f/8.0f, w8, u8);
  union { unsigned u[4]; short8 s; } r;
  r.u[0] = pack2_bf16_fast(p1, p2);
  r.u[1] = pack2_bf16_fast(p3, p4);
  r.u[2] = pack2_bf16_fast(p5, p6);
  r.u[3] = pack2_bf16_fast(p7, p8);
  return r.s;
}

// ---- kernel 1: c_basis fp32 -> bf16, transposed to ws[i][o][d] (256 KB) ----
__global__ void conv_kernel(const float* __restrict__ cb, unsigned short* __restrict__ ws) {
  int t = blockIdx.x * 256 + threadIdx.x;   // 0..16383
  int o = t & 63;
  int i = t >> 6;
  const floatx4* s = (const floatx4*)(cb + ((size_t)o * 256 + i) * 8);
  floatx4 v0 = s[0], v1 = s[1];
  uintx4 w;
  w.x = pack2_bf16_rn(v0.x, v0.y);
  w.y = pack2_bf16_rn(v0.z, v0.w);
  w.z = pack2_bf16_rn(v1.x, v1.y);
  w.w = pack2_bf16_rn(v1.z, v1.w);
  *(uintx4*)(ws + (size_t)i * 512 + o * 8) = w;
}

// ---- kernel 2: K-split GEMM. 128 threads = 2 waves over the SAME 32 rows,
// wave w handles i in [128w, 128w+128) (32 K-steps). Grid 2048 -> 4 waves/SIMD.
// No barriers in the K-loop; explicit prefetch distance 2 (B) / 4 (x).
#define ITERS 32

__global__ __launch_bounds__(128, 4) void kan_kernel(
    const float* __restrict__ x, const unsigned short* __restrict__ ws,
    const float* __restrict__ bias, float* __restrict__ y) {
  __shared__ floatx4 red[8 * 64];   // 8 KB epilogue reduction buffer

  const int tid  = threadIdx.x;
  const int wid  = tid >> 6;    // 0..1 = K-half
  const int lane = tid & 63;
  const int m    = lane & 15;
  const int q    = lane >> 4;
  const int row_block = blockIdx.x * 32;

  floatx4 acc[2][4];
#pragma unroll
  for (int a = 0; a < 2; ++a)
#pragma unroll
    for (int nt = 0; nt < 4; ++nt) acc[a][nt] = (floatx4){0.f, 0.f, 0.f, 0.f};

  // lane's A-frag at local step s covers i = (wid*32+s)*4 + q, rows m and m+16
  const int r0g = row_block + m;
  const float* xp0 = x + (size_t)r0g * 256 + (size_t)wid * 128 + q;  // +4 per step
  const float* xp1 = xp0 + 16 * 256;
  // B-frag shorts: (global s)*2048 + q*512 + nt*128 + m*8
  const unsigned short* bp = ws + (size_t)wid * 32 * 2048 + q * 512 + m * 8;

  // pipeline buffers: B distance 2 (mod-3), x distance 4 (mod-4)
  short8 fb[3][4];
  float xq0[4], xq1[4];
#pragma unroll
  for (int sp = 0; sp < 2; ++sp)
#pragma unroll
    for (int nt = 0; nt < 4; ++nt)
      fb[sp][nt] = *(const short8*)(bp + (size_t)sp * 2048 + nt * 128);
#pragma unroll
  for (int sp = 0; sp < 4; ++sp) {
    xq0[sp] = xp0[sp * 4];
    xq1[sp] = xp1[sp * 4];
  }

#pragma unroll
  for (int s = 0; s < ITERS; ++s) {
    // consume this step's x BEFORE overwriting its queue slot
    float xv0 = xq0[s & 3];
    float xv1 = xq1[s & 3];
    // issue prefetches (compile-time guarded; loads stay in flight, vmcnt(N>0))
    if (s + 2 < ITERS) {
#pragma unroll
      for (int nt = 0; nt < 4; ++nt)
        fb[(s + 2) % 3][nt] = *(const short8*)(bp + (size_t)(s + 2) * 2048 + nt * 128);
    }
    if (s + 4 < ITERS) {
      xq0[s & 3] = xp0[(s + 4) * 4];
      xq1[s & 3] = xp1[(s + 4) * 4];
    }

    short8 fa0 = legendre_frag(xv0);
    short8 fa1 = legendre_frag(xv1);
    const int b = s % 3;
    acc[0][0] = __builtin_amdgcn_mfma_f32_16x16x32_bf16(fa0, fb[b][0], acc[0][0], 0, 0, 0);
    acc[1][0] = __builtin_amdgcn_mfma_f32_16x16x32_bf16(fa1, fb[b][0], acc[1][0], 0, 0, 0);
    acc[0][1] = __builtin_amdgcn_mfma_f32_16x16x32_bf16(fa0, fb[b][1], acc[0][1], 0, 0, 0);
    acc[1][1] = __builtin_amdgcn_mfma_f32_16x16x32_bf16(fa1, fb[b][1], acc[1][1], 0, 0, 0);
    acc[0][2] = __builtin_amdgcn_mfma_f32_16x16x32_bf16(fa0, fb[b][2], acc[0][2], 0, 0, 0);
    acc[1][2] = __builtin_amdgcn_mfma_f32_16x16x32_bf16(fa1, fb[b][2], acc[1][2], 0, 0, 0);
    acc[0][3] = __builtin_amdgcn_mfma_f32_16x16x32_bf16(fa0, fb[b][3], acc[0][3], 0, 0, 0);
    acc[1][3] = __builtin_amdgcn_mfma_f32_16x16x32_bf16(fa1, fb[b][3], acc[1][3], 0, 0, 0);
  }

  // ---- cross-wave K-reduction + epilogue ----
  if (wid == 1) {
#pragma unroll
    for (int a = 0; a < 2; ++a)
#pragma unroll
      for (int nt = 0; nt < 4; ++nt)
        red[(a * 4 + nt) * 64 + lane] = acc[a][nt];
  }
  __syncthreads();
  if (wid == 0) {
    float bv[4];
#pragma unroll
    for (int nt = 0; nt < 4; ++nt) bv[nt] = bias[nt * 16 + m];
#pragma unroll
    for (int a = 0; a < 2; ++a) {
      int gr0 = row_block + a * 16 + q * 4;   // D[row=q*4+reg][col=m]
#pragma unroll
      for (int nt = 0; nt < 4; ++nt) {
        floatx4 p = red[(a * 4 + nt) * 64 + lane];
#pragma unroll
        for (int r = 0; r < 4; ++r) {
          y[(size_t)(gr0 + r) * 64 + nt * 16 + m] = acc[a][nt][r] + p[r] + bv[nt];
        }
      }
    }
  }
}

extern "C" void kernel_launch(void* const* d_in, const int* in_sizes, int n_in,
                              void* d_out, int out_size, void* d_ws, size_t ws_size,
                              hipStream_t stream) {
  const float* x    = (const float*)d_in[0];
  const float* cb   = (const float*)d_in[1];
  const float* bias = (const float*)d_in[2];
  float* y = (float*)d_out;
  unsigned short* ws = (unsigned short*)d_ws;
  int batch = in_sizes[0] / 256;  // 65536
  hipLaunchKernelGGL(conv_kernel, dim3(64), dim3(256), 0, stream, cb, ws);
  hipLaunchKernelGGL(kan_kernel, dim3(batch / 32), dim3(128), 0, stream, x, ws, bias, y);
}

// Round 6
// 123.269 us; speedup vs baseline: 1.1347x; 1.1347x over previous
//
#include <hip/hip_runtime.h>
#include <hip/hip_bf16.h>

typedef __attribute__((ext_vector_type(8))) short short8;
typedef __attribute__((ext_vector_type(4))) float floatx4;
typedef __attribute__((ext_vector_type(4))) unsigned int uintx4;

#define GLOBAL_AS __attribute__((address_space(1)))
#define LDS_AS __attribute__((address_space(3)))

// async 16B/lane global->LDS DMA. LDS dest = WAVE-uniform base + lane*16.
// Fire-and-forget: no register result => compiler cannot sink it to the use.
__device__ __forceinline__ void async_ld16(const void* g, void* l) {
  __builtin_amdgcn_global_load_lds((const GLOBAL_AS unsigned int*)g,
                                   (LDS_AS unsigned int*)l, 16, 0, 0);
}

// accurate pack (conv kernel only)
__device__ __forceinline__ unsigned pack2_bf16_rn(float a, float b) {
  __hip_bfloat162 h = __float22bfloat162_rn(make_float2(a, b));
  unsigned r;
  __builtin_memcpy(&r, &h, 4);
  return r;
}

// fast pack: +0x8000 (RN ties-away, inputs finite) + byte perm. 3 VALU ops.
__device__ __forceinline__ unsigned pack2_bf16_fast(float a, float b) {
  unsigned ua, ub;
  __builtin_memcpy(&ua, &a, 4);
  __builtin_memcpy(&ub, &b, 4);
  return __builtin_amdgcn_perm(ub + 0x8000u, ua + 0x8000u, 0x07060302u);
}

// tanh + Legendre P1..P8 -> 8-bf16 MFMA A-fragment (~26 math + 12 pack VALU)
__device__ __forceinline__ short8 legendre_frag(float xv) {
  float e  = __builtin_amdgcn_exp2f(xv * 2.885390081777927f); // 2*log2(e)
  float t  = 1.0f - 2.0f * __builtin_amdgcn_rcpf(e + 1.0f);
  float p1 = t;
  float u2 = t * p1,  w2 = u2 - 1.0f;  float p2 = fmaf(0.5f, w2, u2);
  float u3 = t * p2,  w3 = u3 - p1;    float p3 = fmaf(2.0f/3.0f, w3, u3);
  float u4 = t * p3,  w4 = u4 - p2;    float p4 = fmaf(0.75f, w4, u4);
  float u5 = t * p4,  w5 = u5 - p3;    float p5 = fmaf(0.8f, w5, u5);
  float u6 = t * p5,  w6 = u6 - p4;    float p6 = fmaf(5.0f/6.0f, w6, u6);
  float u7 = t * p6,  w7 = u7 - p5;    float p7 = fmaf(6.0f/7.0f, w7, u7);
  float u8 = t * p7,  w8 = u8 - p6;    float p8 = fmaf(7.0f/8.0f, w8, u8);
  union { unsigned u[4]; short8 s; } r;
  r.u[0] = pack2_bf16_fast(p1, p2);
  r.u[1] = pack2_bf16_fast(p3, p4);
  r.u[2] = pack2_bf16_fast(p5, p6);
  r.u[3] = pack2_bf16_fast(p7, p8);
  return r.s;
}

// ---- kernel 1: c_basis fp32 -> bf16, transposed to ws[i][o][d] (256 KB) ----
// coalesced 32B reads; scattered 16B writes (only 256 KB total, L2-absorbed)
__global__ void conv_kernel(const float* __restrict__ cb, unsigned short* __restrict__ ws) {
  int t = blockIdx.x * 256 + threadIdx.x;   // 0..16383
  int o = t >> 8;
  int i = t & 255;
  const floatx4* s = (const floatx4*)(cb + ((size_t)o * 256 + i) * 8);
  floatx4 v0 = s[0], v1 = s[1];
  uintx4 w;
  w.x = pack2_bf16_rn(v0.x, v0.y);
  w.y = pack2_bf16_rn(v0.z, v0.w);
  w.z = pack2_bf16_rn(v1.x, v1.y);
  w.w = pack2_bf16_rn(v1.z, v1.w);
  *(uintx4*)(ws + (size_t)i * 512 + o * 8) = w;
}

// ---- kernel 2: chunked DMA double-buffer with RAW s_barrier + vmcnt(N>0). ----
// 256 thr (4 waves), 128 rows/block, 16 chunks x 16 i (4 K-steps). Prefetch for
// chunk ch+1 issued BEFORE waiting on chunk ch => wait covers a whole chunk of
// compute; the barrier never drains in-flight DMA (no __syncthreads anywhere).
#define MB 128
#define NCH 16

__global__ __launch_bounds__(256, 2) void kan_kernel(
    const float* __restrict__ x, const unsigned short* __restrict__ ws,
    const float* __restrict__ bias, float* __restrict__ y) {
  __shared__ __align__(16) unsigned short bt[2][16 * 64 * 8]; // 2 x 16 KB
  __shared__ __align__(16) float xs[2][MB * 16];              // 2 x 8 KB

  const int tid  = threadIdx.x;
  const int wid  = tid >> 6;    // 0..3
  const int lane = tid & 63;
  const int m    = lane & 15;
  const int q    = lane >> 4;
  const int row_block = blockIdx.x * MB;

  floatx4 acc[2][4];
#pragma unroll
  for (int a = 0; a < 2; ++a)
#pragma unroll
    for (int nt = 0; nt < 4; ++nt) acc[a][nt] = (floatx4){0.f, 0.f, 0.f, 0.f};

  // 6 DMA loads per wave per chunk: 4 for B (16 KB) + 2 for x (8 KB)
  auto stage = [&](int ch, int buf) {
#pragma unroll
    for (int t = 0; t < 4; ++t) {
      int sb = t * 256 + wid * 64;  // wave-uniform slot base
      async_ld16(ws + (size_t)ch * 8192 + (size_t)(sb + lane) * 8, &bt[buf][sb * 8]);
    }
#pragma unroll
    for (int t = 0; t < 2; ++t) {
      int sb = t * 256 + wid * 64;
      int slot = sb + lane;
      int r = slot >> 2;
      int c4 = (slot & 3) ^ (r & 3);  // xor swizzle on 16B blocks
      async_ld16(x + (size_t)(row_block + r) * 256 + ch * 16 + c4 * 4, &xs[buf][sb * 4]);
    }
  };

  // x read byte-offsets: addr = xoff ^ (ks<<4) (bits 4-5 free; swizzle folded)
  const int xoff0 = (wid * 32 + m) * 64 + ((m & 3) << 4) + q * 4;
  const int xoff1 = xoff0 + 16 * 64;

  stage(0, 0);
#pragma unroll 2
  for (int ch = 0; ch < NCH; ++ch) {
    const int buf = ch & 1;
    // WAR: all waves done reading buf^1 (chunk ch-1) before DMA overwrites it.
    asm volatile("s_barrier" ::: "memory");
    if (ch + 1 < NCH) {
      stage(ch + 1, buf ^ 1);
      // wait chunk ch's 6 DMAs; chunk ch+1's 6 stay in flight across compute
      asm volatile("s_waitcnt vmcnt(6)" ::: "memory");
    } else {
      asm volatile("s_waitcnt vmcnt(0)" ::: "memory");
    }

    const unsigned short* bp = &bt[buf][q * 512 + m * 8];
    const char* xb = (const char*)&xs[buf][0];
#pragma unroll
    for (int ks = 0; ks < 4; ++ks) {
      short8 fb0 = *(const short8*)(bp + ks * 2048 + 0 * 128);
      short8 fb1 = *(const short8*)(bp + ks * 2048 + 1 * 128);
      short8 fb2 = *(const short8*)(bp + ks * 2048 + 2 * 128);
      short8 fb3 = *(const short8*)(bp + ks * 2048 + 3 * 128);
      float xv0 = *(const float*)(xb + (xoff0 ^ (ks << 4)));
      float xv1 = *(const float*)(xb + (xoff1 ^ (ks << 4)));
      short8 fa0 = legendre_frag(xv0);
      short8 fa1 = legendre_frag(xv1);
      acc[0][0] = __builtin_amdgcn_mfma_f32_16x16x32_bf16(fa0, fb0, acc[0][0], 0, 0, 0);
      acc[1][0] = __builtin_amdgcn_mfma_f32_16x16x32_bf16(fa1, fb0, acc[1][0], 0, 0, 0);
      acc[0][1] = __builtin_amdgcn_mfma_f32_16x16x32_bf16(fa0, fb1, acc[0][1], 0, 0, 0);
      acc[1][1] = __builtin_amdgcn_mfma_f32_16x16x32_bf16(fa1, fb1, acc[1][1], 0, 0, 0);
      acc[0][2] = __builtin_amdgcn_mfma_f32_16x16x32_bf16(fa0, fb2, acc[0][2], 0, 0, 0);
      acc[1][2] = __builtin_amdgcn_mfma_f32_16x16x32_bf16(fa1, fb2, acc[1][2], 0, 0, 0);
      acc[0][3] = __builtin_amdgcn_mfma_f32_16x16x32_bf16(fa0, fb3, acc[0][3], 0, 0, 0);
      acc[1][3] = __builtin_amdgcn_mfma_f32_16x16x32_bf16(fa1, fb3, acc[1][3], 0, 0, 0);
    }
  }

  // epilogue: D[row=(q*4+reg)][col=m], add bias (no cross-wave reduction)
  float bv[4];
#pragma unroll
  for (int nt = 0; nt < 4; ++nt) bv[nt] = bias[nt * 16 + m];
#pragma unroll
  for (int a = 0; a < 2; ++a) {
    int gr0 = row_block + wid * 32 + a * 16 + q * 4;
#pragma unroll
    for (int nt = 0; nt < 4; ++nt) {
#pragma unroll
      for (int r = 0; r < 4; ++r) {
        y[(size_t)(gr0 + r) * 64 + nt * 16 + m] = acc[a][nt][r] + bv[nt];
      }
    }
  }
}

extern "C" void kernel_launch(void* const* d_in, const int* in_sizes, int n_in,
                              void* d_out, int out_size, void* d_ws, size_t ws_size,
                              hipStream_t stream) {
  const float* x    = (const float*)d_in[0];
  const float* cb   = (const float*)d_in[1];
  const float* bias = (const float*)d_in[2];
  float* y = (float*)d_out;
  unsigned short* ws = (unsigned short*)d_ws;
  int batch = in_sizes[0] / 256;  // 65536
  hipLaunchKernelGGL(conv_kernel, dim3(64), dim3(256), 0, stream, cb, ws);
  hipLaunchKernelGGL(kan_kernel, dim3(batch / MB), dim3(256), 0, stream, x, ws, bias, y);
}

// Round 7
// 120.421 us; speedup vs baseline: 1.1615x; 1.0236x over previous
//
#include <hip/hip_runtime.h>
#include <hip/hip_bf16.h>

typedef _Float16 half2v __attribute__((ext_vector_type(2)));
typedef _Float16 half8  __attribute__((ext_vector_type(8)));
typedef __attribute__((ext_vector_type(4))) float floatx4;
typedef __attribute__((ext_vector_type(4))) unsigned int uintx4;

#define GLOBAL_AS __attribute__((address_space(1)))
#define LDS_AS __attribute__((address_space(3)))

// async 16B/lane global->LDS DMA. LDS dest = WAVE-uniform base + lane*16.
__device__ __forceinline__ void async_ld16(const void* g, void* l) {
  __builtin_amdgcn_global_load_lds((const GLOBAL_AS unsigned int*)g,
                                   (LDS_AS unsigned int*)l, 16, 0, 0);
}

__device__ __forceinline__ half2v h2(float v) {
  return (half2v){(_Float16)v, (_Float16)v};
}

// tanh(x0),tanh(x1) -> packed-f16 Legendre P1..P8 for BOTH rows.
// fa0 = low halves (row0), fa1 = high halves (row1). ~42 VALU total.
__device__ __forceinline__ void legendre2_f16(float xv0, float xv1,
                                              half8* fa0, half8* fa1) {
  float e0 = __builtin_amdgcn_exp2f(xv0 * 2.885390081777927f); // 2*log2(e)
  float t0 = 1.0f - 2.0f * __builtin_amdgcn_rcpf(e0 + 1.0f);
  float e1 = __builtin_amdgcn_exp2f(xv1 * 2.885390081777927f);
  float t1 = 1.0f - 2.0f * __builtin_amdgcn_rcpf(e1 + 1.0f);
  half2v t;
  { auto tt = __builtin_amdgcn_cvt_pkrtz(t0, t1); __builtin_memcpy(&t, &tt, 4); }
  // P_k = u + c_k*(u - P_{k-2}), u = t*P_{k-1}, c_k=(k-1)/k   (packed, 3 ops/deg)
  half2v p1 = t;
  half2v u2 = t * p1, w2 = u2 - h2(1.0f);  half2v p2 = h2(0.5f)      * w2 + u2;
  half2v u3 = t * p2, w3 = u3 - p1;        half2v p3 = h2(2.0f/3.0f) * w3 + u3;
  half2v u4 = t * p3, w4 = u4 - p2;        half2v p4 = h2(0.75f)     * w4 + u4;
  half2v u5 = t * p4, w5 = u5 - p3;        half2v p5 = h2(0.8f)      * w5 + u5;
  half2v u6 = t * p5, w6 = u6 - p4;        half2v p6 = h2(5.0f/6.0f) * w6 + u6;
  half2v u7 = t * p6, w7 = u7 - p5;        half2v p7 = h2(6.0f/7.0f) * w7 + u7;
  half2v u8 = t * p7, w8 = u8 - p6;        half2v p8 = h2(7.0f/8.0f) * w8 + u8;
  unsigned P[8];
  __builtin_memcpy(&P[0], &p1, 4); __builtin_memcpy(&P[1], &p2, 4);
  __builtin_memcpy(&P[2], &p3, 4); __builtin_memcpy(&P[3], &p4, 4);
  __builtin_memcpy(&P[4], &p5, 4); __builtin_memcpy(&P[5], &p6, 4);
  __builtin_memcpy(&P[6], &p7, 4); __builtin_memcpy(&P[7], &p8, 4);
  union { unsigned u[4]; half8 h; } a0, a1;
#pragma unroll
  for (int j = 0; j < 4; ++j) {
    // perm: sel bytes 0-3 pick src1, 4-7 pick src0
    a0.u[j] = __builtin_amdgcn_perm(P[2*j+1], P[2*j], 0x05040100u); // low halves
    a1.u[j] = __builtin_amdgcn_perm(P[2*j+1], P[2*j], 0x07060302u); // high halves
  }
  *fa0 = a0.h;
  *fa1 = a1.h;
}

// ---- kernel 1: c_basis fp32 -> f16, transposed to ws[i][o][d] (256 KB) ----
__global__ void conv_kernel(const float* __restrict__ cb, _Float16* __restrict__ ws) {
  int t = blockIdx.x * 128 + threadIdx.x;   // 0..16383 = (o,i)
  int o = t >> 8;
  int i = t & 255;
  const floatx4* s = (const floatx4*)(cb + ((size_t)o * 256 + i) * 8);
  floatx4 v0 = s[0], v1 = s[1];
  union { _Float16 h[8]; uintx4 u; } w;
  w.h[0] = (_Float16)v0.x; w.h[1] = (_Float16)v0.y;
  w.h[2] = (_Float16)v0.z; w.h[3] = (_Float16)v0.w;
  w.h[4] = (_Float16)v1.x; w.h[5] = (_Float16)v1.y;
  w.h[6] = (_Float16)v1.z; w.h[7] = (_Float16)v1.w;
  *(uintx4*)(ws + (size_t)i * 512 + o * 8) = w.u;
}

// ---- kernel 2: DMA double-buffer, raw s_barrier pair + vmcnt(N>0). ----
// 128 thr (2 waves), 64 rows/block, grid 1024 -> 4 blocks/CU (LDS 40 KB).
// 16 chunks x 16 i (4 K-steps). Chunk ch+1's DMAs stay in flight across
// chunk ch's compute. Barrier pair per chunk: WAR (top) + RAW (post-vmcnt).
#define MB 64
#define NCH 16

__global__ __launch_bounds__(128, 2) void kan_kernel(
    const float* __restrict__ x, const _Float16* __restrict__ ws,
    const float* __restrict__ bias, float* __restrict__ y) {
  __shared__ __align__(16) _Float16 bt[2][16 * 64 * 8]; // 2 x 16 KB
  __shared__ __align__(16) float xs[2][MB * 16];        // 2 x 4 KB

  const int tid  = threadIdx.x;
  const int wid  = tid >> 6;    // 0..1
  const int lane = tid & 63;
  const int m    = lane & 15;
  const int q    = lane >> 4;
  const int row_block = blockIdx.x * MB;

  floatx4 acc[2][4];
#pragma unroll
  for (int a = 0; a < 2; ++a)
#pragma unroll
    for (int nt = 0; nt < 4; ++nt) acc[a][nt] = (floatx4){0.f, 0.f, 0.f, 0.f};

  // persistent staging pointers (advance once per chunk; no per-chunk rebuild)
  const _Float16* bsrc[8];
#pragma unroll
  for (int t = 0; t < 8; ++t)
    bsrc[t] = ws + (size_t)(t * 128 + wid * 64 + lane) * 8;
  const float* xsrc[2];
#pragma unroll
  for (int t = 0; t < 2; ++t) {
    int slot = t * 128 + wid * 64 + lane;
    int r = slot >> 2;
    int c4 = (slot & 3) ^ (r & 3);   // xor swizzle on 16B units
    xsrc[t] = x + (size_t)(row_block + r) * 256 + c4 * 4;
  }

  // 10 DMAs per wave per chunk: 8 B-slots (16 KB) + 2 x-slots (4 KB)
  auto stage = [&](int buf) {
#pragma unroll
    for (int t = 0; t < 8; ++t) {
      int sb = t * 128 + wid * 64;
      async_ld16(bsrc[t], &bt[buf][sb * 8]);
      bsrc[t] += 8192;
    }
#pragma unroll
    for (int t = 0; t < 2; ++t) {
      int sb = t * 128 + wid * 64;
      async_ld16(xsrc[t], &xs[buf][sb * 4]);
      xsrc[t] += 16;
    }
  };

  // x read byte-offsets: addr = xoff ^ (ks<<4); rows r0=wid*32+m, r1=r0+16
  const int xoff0 = (wid * 32 + m) * 64 + ((m & 3) << 4) + q * 4;
  const int xoff1 = xoff0 + 1024;

  stage(0);
#pragma unroll 2
  for (int ch = 0; ch < NCH; ++ch) {
    const int buf = ch & 1;
    // WAR: all waves done computing chunk ch-1 (which read buf^1)
    asm volatile("s_barrier" ::: "memory");
    if (ch + 1 < NCH) {
      stage(buf ^ 1);
      asm volatile("s_waitcnt vmcnt(10)" ::: "memory"); // own chunk-ch landed
    } else {
      asm volatile("s_waitcnt vmcnt(0)" ::: "memory");
    }
    // RAW: ALL waves' chunk-ch slices landed (fixes R6 cross-wave race)
    asm volatile("s_barrier" ::: "memory");

    const _Float16* bp = &bt[buf][q * 512 + m * 8];
    const char* xb = (const char*)&xs[buf][0];
#pragma unroll
    for (int ks = 0; ks < 4; ++ks) {
      half8 fb0 = *(const half8*)(bp + ks * 2048 + 0 * 128);
      half8 fb1 = *(const half8*)(bp + ks * 2048 + 1 * 128);
      half8 fb2 = *(const half8*)(bp + ks * 2048 + 2 * 128);
      half8 fb3 = *(const half8*)(bp + ks * 2048 + 3 * 128);
      float xv0 = *(const float*)(xb + (xoff0 ^ (ks << 4)));
      float xv1 = *(const float*)(xb + (xoff1 ^ (ks << 4)));
      half8 fa0, fa1;
      legendre2_f16(xv0, xv1, &fa0, &fa1);
      acc[0][0] = __builtin_amdgcn_mfma_f32_16x16x32_f16(fa0, fb0, acc[0][0], 0, 0, 0);
      acc[1][0] = __builtin_amdgcn_mfma_f32_16x16x32_f16(fa1, fb0, acc[1][0], 0, 0, 0);
      acc[0][1] = __builtin_amdgcn_mfma_f32_16x16x32_f16(fa0, fb1, acc[0][1], 0, 0, 0);
      acc[1][1] = __builtin_amdgcn_mfma_f32_16x16x32_f16(fa1, fb1, acc[1][1], 0, 0, 0);
      acc[0][2] = __builtin_amdgcn_mfma_f32_16x16x32_f16(fa0, fb2, acc[0][2], 0, 0, 0);
      acc[1][2] = __builtin_amdgcn_mfma_f32_16x16x32_f16(fa1, fb2, acc[1][2], 0, 0, 0);
      acc[0][3] = __builtin_amdgcn_mfma_f32_16x16x32_f16(fa0, fb3, acc[0][3], 0, 0, 0);
      acc[1][3] = __builtin_amdgcn_mfma_f32_16x16x32_f16(fa1, fb3, acc[1][3], 0, 0, 0);
    }
  }

  // epilogue: D[row=(q*4+reg)][col=m], add bias (layout verified R1-R6)
  float bv[4];
#pragma unroll
  for (int nt = 0; nt < 4; ++nt) bv[nt] = bias[nt * 16 + m];
#pragma unroll
  for (int a = 0; a < 2; ++a) {
    int gr0 = row_block + wid * 32 + a * 16 + q * 4;
#pragma unroll
    for (int nt = 0; nt < 4; ++nt) {
#pragma unroll
      for (int r = 0; r < 4; ++r) {
        y[(size_t)(gr0 + r) * 64 + nt * 16 + m] = acc[a][nt][r] + bv[nt];
      }
    }
  }
}

extern "C" void kernel_launch(void* const* d_in, const int* in_sizes, int n_in,
                              void* d_out, int out_size, void* d_ws, size_t ws_size,
                              hipStream_t stream) {
  const float* x    = (const float*)d_in[0];
  const float* cb   = (const float*)d_in[1];
  const float* bias = (const float*)d_in[2];
  float* y = (float*)d_out;
  _Float16* ws = (_Float16*)d_ws;
  int batch = in_sizes[0] / 256;  // 65536
  hipLaunchKernelGGL(conv_kernel, dim3(128), dim3(128), 0, stream, cb, ws);
  hipLaunchKernelGGL(kan_kernel, dim3(batch / MB), dim3(128), 0, stream, x, ws, bias, y);
}